// Round 8
// baseline (178.503 us; speedup 1.0000x reference)
//
#include <hip/hip_runtime.h>

#define S_LEN 2048
#define E_DIM 1024
#define H_NUM 16
#define D_DIM 64

typedef unsigned short u16;
using bf16x8 = __attribute__((ext_vector_type(8))) short;   // 8 bf16 in 4 VGPRs
using f32x4  = __attribute__((ext_vector_type(4))) float;
using f32x16 = __attribute__((ext_vector_type(16))) float;

#define MFMA16(A, B, C) __builtin_amdgcn_mfma_f32_16x16x32_bf16(A, B, C, 0, 0, 0)
#define MFMA32(A, B, C) __builtin_amdgcn_mfma_f32_32x32x16_bf16(A, B, C, 0, 0, 0)
#define QSCALE 0.18033688011112042f   // (1/sqrt(D)) * log2(e), folded into Q so attn uses exp2

__device__ __forceinline__ u16 f2bf(float f) {
    unsigned u = __float_as_uint(f);
    u += 0x7fffu + ((u >> 16) & 1u);            // RNE
    return (u16)(u >> 16);
}
__device__ __forceinline__ f32x4 fzero4() { f32x4 z; z[0]=0.f; z[1]=0.f; z[2]=0.f; z[3]=0.f; return z; }
__device__ __forceinline__ f32x16 fzero16() {
    f32x16 z;
    #pragma unroll
    for (int i = 0; i < 16; i++) z[i] = 0.f;
    return z;
}

// packed f32x2 -> bf16x2 (RNE)
__device__ __forceinline__ unsigned cvtpk(float a, float b) {
    unsigned r;
    asm("v_cvt_pk_bf16_f32 %0, %1, %2" : "=v"(r) : "v"(a), "v"(b));
    return r;
}
__device__ __forceinline__ float fexp2(float x) {
#if __has_builtin(__builtin_amdgcn_exp2f)
    return __builtin_amdgcn_exp2f(x);
#else
    float r; asm("v_exp_f32 %0, %1" : "=v"(r) : "v"(x)); return r;
#endif
}
__device__ __forceinline__ float frcp(float x) {
#if __has_builtin(__builtin_amdgcn_rcpf)
    return __builtin_amdgcn_rcpf(x);
#else
    float r; asm("v_rcp_f32 %0, %1" : "=v"(r) : "v"(x)); return r;
#endif
}

// async global->LDS, 16B per lane; LDS dest = wave-uniform base + lane*16
__device__ __forceinline__ void gll16(const u16* g, u16* l) {
    __builtin_amdgcn_global_load_lds(
        (const __attribute__((address_space(1))) void*)g,
        (__attribute__((address_space(3))) void*)l, 16, 0, 0);
}

// ---- swizzled 64x64 u16 tile staging via global_load_lds (both-sides XOR swizzle) ----
// LDS row r at bytes r*128; physical 16B slot s holds logical slot s^(r&7).
__device__ __forceinline__ void stage64(const u16* __restrict__ g, int gstride,
                                        u16* l, int wave, int lane) {
    #pragma unroll
    for (int i = 0; i < 2; i++) {
        const int r  = wave * 16 + i * 8 + (lane >> 3);
        const int sl = (lane & 7) ^ (r & 7);
        gll16(g + (size_t)r * gstride + sl * 8, l + (wave * 16 + i * 8) * 64);
    }
}
// read one bf16x8 fragment = logical u16 cols [(hh*4+quad)*8 .. +7] of row rr
__device__ __forceinline__ bf16x8 ldswz(const u16* t, int rr, int hh, int quad) {
    const int sl = ((hh << 2) + quad) ^ (rr & 7);
    return *(const bf16x8*)(t + rr * 64 + sl * 8);
}
// generic fragment read: row rr (0..63), logical 16B slot sl (0..7)
__device__ __forceinline__ bf16x8 ldfr(const u16* t, int rr, int sl) {
    return *(const bf16x8*)(t + rr * 64 + ((sl ^ (rr & 7)) * 8));
}

// ---------------- fp32 [R,C] tile -> bf16 [C,R] transpose-convert helper ----------------
__device__ __forceinline__ void cvt_t_tile(const float* __restrict__ bin, u16* __restrict__ bout,
                                           int R, int C, int r0, int c0) {
    __shared__ float t[64][65];
    const int tid = threadIdx.x;
    const int lr = tid >> 2, lc = (tid & 3) * 16;

    const float* src = bin + (size_t)(r0 + lr) * C + c0 + lc;
    #pragma unroll
    for (int j = 0; j < 4; j++) {
        float4 f = *(const float4*)(src + j * 4);
        t[lr][lc + j * 4 + 0] = f.x; t[lr][lc + j * 4 + 1] = f.y;
        t[lr][lc + j * 4 + 2] = f.z; t[lr][lc + j * 4 + 3] = f.w;
    }
    __syncthreads();

    u16* dst = bout + (size_t)(c0 + lr) * R + r0 + lc;
    u16 vals[16];
    #pragma unroll
    for (int i = 0; i < 16; i++) vals[i] = f2bf(t[lc + i][lr]);
    uint4 pa, pb;
    pa.x = vals[0] | (vals[1] << 16);  pa.y = vals[2] | (vals[3] << 16);
    pa.z = vals[4] | (vals[5] << 16);  pa.w = vals[6] | (vals[7] << 16);
    pb.x = vals[8] | (vals[9] << 16);  pb.y = vals[10] | (vals[11] << 16);
    pb.z = vals[12] | (vals[13] << 16); pb.w = vals[14] | (vals[15] << 16);
    *(uint4*)dst = pa;
    *(uint4*)(dst + 8) = pb;
}

// ---------------- merged precompute: x->bf16 | Wq/Wk/Wv transpose | Wp transpose ----------------
__global__ __launch_bounds__(256) void cvt_all(
    const float* __restrict__ x, u16* __restrict__ xb, int n,
    const float* __restrict__ Wq, const float* __restrict__ Wk, const float* __restrict__ Wv,
    u16* __restrict__ wqt, u16* __restrict__ wkt, u16* __restrict__ wvt,
    const float* __restrict__ Wp, u16* __restrict__ wpt)
{
    const int bid = blockIdx.x;
    if (bid < 4096) {
        int i4 = (bid * 256 + threadIdx.x) * 4;
        if (i4 < n) {
            float4 f = *(const float4*)(x + i4);
            unsigned lo = (unsigned)f2bf(f.x) | ((unsigned)f2bf(f.y) << 16);
            unsigned hi = (unsigned)f2bf(f.z) | ((unsigned)f2bf(f.w) << 16);
            uint2 p; p.x = lo; p.y = hi;
            *(uint2*)(xb + i4) = p;
        }
    } else if (bid < 4096 + 768) {
        const int t  = bid - 4096;
        const int z  = t >> 4;           // 0..47
        const int ry = t & 15;           // 0..15
        const int which = z >> 4, bh = z & 15;
        const float* in = (which == 0) ? Wq : (which == 1) ? Wk : Wv;
        u16* outp = (which == 0) ? wqt : (which == 1) ? wkt : wvt;
        cvt_t_tile(in + (size_t)bh * E_DIM * D_DIM, outp + (size_t)bh * E_DIM * D_DIM,
                   E_DIM, D_DIM, ry * 64, 0);
    } else {
        const int t = bid - (4096 + 768); // 0..255
        cvt_t_tile(Wp, wpt, H_NUM * D_DIM, E_DIM, (t >> 4) * 64, (t & 15) * 64);
    }
}

// ---------------- QKV as one fused GEMM: M=4096, N=3072, K=1024 (r7-frozen) ----------------
__global__ __launch_bounds__(128, 2) void qkv_gemm(
    const u16* __restrict__ xb, const u16* __restrict__ wcat,
    const float* __restrict__ bq, const float* __restrict__ bk, const float* __restrict__ bv,
    u16* __restrict__ oq, u16* __restrict__ okk, u16* __restrict__ ov)
{
    const int m0 = blockIdx.x * 128;   // 0..31
    const int n0 = blockIdx.y * 128;   // 0..23

    __shared__ u16 As[2][64 * 64];     // 8 KB per buffer
    __shared__ u16 Bs[2][64 * 64];

    const int tid  = threadIdx.x;      // 0..127
    const int wave = tid >> 6, lane = tid & 63, quad = lane >> 4, l16 = lane & 15;

    f32x4 acc[8][4];                   // [j=n-frag 0..7][mi=m-frag 0..3]
    #pragma unroll
    for (int j = 0; j < 8; j++)
        #pragma unroll
        for (int mi = 0; mi < 4; mi++) acc[j][mi] = fzero4();

#define STAGE(K0, BUF)                                                               \
    _Pragma("unroll")                                                                \
    for (int i = 0; i < 2; i++) {                                                    \
        const int r  = wave * 32 + i * 8 + (lane >> 3);   /* LDS row 0..63 */        \
        const int s  = (lane & 7) ^ (r & 7);              /* logical slot  */        \
        const int mr = r + ((s >> 2) << 6);               /* m/n-row 0..127 */       \
        const int kc = (s & 3) * 8;                       /* k-col base     */       \
        gll16(xb   + (size_t)(m0 + mr) * E_DIM + (K0) + kc,                          \
              &As[BUF][(wave * 32 + i * 8) * 64]);                                   \
        gll16(wcat + (size_t)(n0 + mr) * E_DIM + (K0) + kc,                          \
              &Bs[BUF][(wave * 32 + i * 8) * 64]);                                   \
        const int r2  = wave * 32 + 16 + i * 8 + (lane >> 3);                        \
        const int s2  = (lane & 7) ^ (r2 & 7);                                       \
        const int mr2 = r2 + ((s2 >> 2) << 6);                                       \
        const int kc2 = (s2 & 3) * 8;                                                \
        gll16(xb   + (size_t)(m0 + mr2) * E_DIM + (K0) + kc2,                        \
              &As[BUF][(wave * 32 + 16 + i * 8) * 64]);                              \
        gll16(wcat + (size_t)(n0 + mr2) * E_DIM + (K0) + kc2,                        \
              &Bs[BUF][(wave * 32 + 16 + i * 8) * 64]);                              \
    }

    STAGE(0, 0);

    for (int kt = 0; kt < 32; kt++) {
        __syncthreads();
        if (kt < 31) {
            const int kn = (kt + 1) * 32;
            if ((kt & 1) == 0) { STAGE(kn, 1); } else { STAGE(kn, 0); }
        }
        const u16* Ac = As[kt & 1];
        const u16* Bc = Bs[kt & 1];

        bf16x8 af[4];
        #pragma unroll
        for (int mi = 0; mi < 4; mi++) {
            const int row = mi * 16 + l16;
            af[mi] = *(const bf16x8*)(&Ac[row * 64 + ((((wave << 2) + quad)) ^ (row & 7)) * 8]);
        }
        __builtin_amdgcn_s_setprio(1);
        #pragma unroll
        for (int j = 0; j < 8; j++) {
            const int row = (j & 3) * 16 + l16;
            bf16x8 bfv = *(const bf16x8*)(&Bc[row * 64 +
                              ((((j >> 2) << 2) + quad) ^ (row & 7)) * 8]);
            #pragma unroll
            for (int mi = 0; mi < 4; mi++)
                acc[j][mi] = MFMA16(af[mi], bfv, acc[j][mi]);
        }
        __builtin_amdgcn_s_setprio(0);
    }
#undef STAGE

    const int t = n0 >> 10;
    if (t < 2) {
        const float scl = (t == 0) ? QSCALE : 1.0f;
        const float* bias = (t == 0) ? bq : bk;
        u16* dst = (t == 0) ? oq : okk;
        #pragma unroll
        for (int j = 0; j < 8; j++) {
            const int n = n0 + j * 16 + l16;
            const int h = (n >> 6) & 15, d = n & 63;
            float bia = bias[h * D_DIM + d];
            #pragma unroll
            for (int mi = 0; mi < 4; mi++) {
                #pragma unroll
                for (int r = 0; r < 4; r++) {
                    int m = m0 + wave * 64 + mi * 16 + quad * 4 + r;
                    int b = m >> 11, s = m & 2047;
                    dst[((size_t)(b * H_NUM + h) * S_LEN + s) * D_DIM + d] =
                        f2bf((acc[j][mi][r] + bia) * scl);
                }
            }
        }
    } else {
        const int b  = m0 >> 11, s0 = m0 & 2047;
        const int h0 = (n0 >> 6) & 15;
        u16* Tb0 = &As[0][0];
        u16* Tb1 = &Bs[0][0];
        #pragma unroll
        for (int pass = 0; pass < 2; ++pass) {
            __syncthreads();
            if (wave == pass) {
                #pragma unroll
                for (int j = 0; j < 8; j++) {
                    const int n = n0 + j * 16 + l16;
                    const int d = n & 63, hh = (n >> 6) & 15;
                    const float bia = bv[hh * D_DIM + d];
                    u16* Tb = (j < 4) ? Tb0 : Tb1;
                    const int nl = (j & 3) * 16 + l16;
                    #pragma unroll
                    for (int mi = 0; mi < 4; mi++) {
                        uint2 pk;
                        pk.x = cvtpk(acc[j][mi][0] + bia, acc[j][mi][1] + bia);
                        pk.y = cvtpk(acc[j][mi][2] + bia, acc[j][mi][3] + bia);
                        *(uint2*)(&Tb[nl * 72 + mi * 16 + quad * 4]) = pk;
                    }
                }
            }
            __syncthreads();
            #pragma unroll
            for (int g = 0; g < 8; ++g) {
                const int rowi = g * 16 + (tid >> 3);
                const int ml = (tid & 7) * 8;
                const u16* srcp = (rowi < 64 ? Tb0 : Tb1) + (rowi & 63) * 72 + ml;
                const int hh = h0 + (rowi >> 6), d = rowi & 63;
                u16* dstp = ov + ((size_t)(b * H_NUM + hh) * D_DIM + d) * S_LEN
                               + s0 + pass * 64 + ml;
                *(uint4*)dstp = *(const uint4*)srcp;
            }
        }
    }
}

// ---------------- flash attention: 32x32 MFMA + in-register P (T12) ----------------
// Waves 0,1 own tile qb (q-halves 0/1); waves 2,3 own tile qa. The S^T C-layout
// (col = lane&31 = q) lane-matches the PV A-operand layout (row = lane&31 = q), so
// P never touches LDS: 16 cvt_pk + 8 permlane32_swap per tile replace the r7 P
// round-trip (32 KB/block-iter of LDS traffic, 29% of an LDS-bound kernel).
// Q is staged through the K/V buffers in the prologue (no Q LDS; total 32.5 KB).
__global__ __launch_bounds__(256, 2) void attn_fwd(
    const u16* __restrict__ q, const u16* __restrict__ k, const u16* __restrict__ vt,
    u16* __restrict__ concat)
{
    const int bid  = blockIdx.x;              // 0..511
    const int halfg = bid >> 8;               // 0 | 1
    const int pi   = (bid & 255) >> 5;        // 0..7
    const int p    = halfg ? (15 - pi) : pi;  // balanced: paired CUs sum to 49 iters
    const int g    = bid & 31;                // (b,h) group; XCD = g&7
    const int hd   = g & 15;
    const int bb   = g >> 4;
    const int qa = p, qb = 31 - p;

    const size_t headoff = (size_t)(bb * H_NUM + hd) * S_LEN * D_DIM;
    const u16* qptr = q  + headoff;
    const u16* kptr = k  + headoff;
    const u16* vptr = vt + headoff;     // [D][S]

    __shared__ u16 Ks[2][64 * 64];      // [kk][d], swizzled, double-buffered
    __shared__ u16 Vts[2][64 * 64];     // [d][sk], swizzled, double-buffered
    __shared__ float Ls[4][32];         // per-wave row sums (epilogue)

    const int tid  = threadIdx.x;
    const int wave = tid >> 6, lane = tid & 63;
    const int l32 = lane & 31, hh = lane >> 5;

    const int mytile = (wave >> 1) ? qa : qb;   // waves 0,1 -> qb; waves 2,3 -> qa
    const int qhalf  = wave & 1;

    // ---- prologue: stage Q tiles through the K/V buffers, hoist to registers ----
    stage64(qptr + (size_t)qb * 64 * D_DIM, D_DIM, Ks[0],  wave, lane);
    stage64(qptr + (size_t)qa * 64 * D_DIM, D_DIM, Vts[0], wave, lane);
    __syncthreads();                    // drains DMA

    bf16x8 qf[4];                       // B-operand: col q = l32, k(d) = c*16 + hh*8
    {
        const u16* Qsrc = (wave >> 1) ? &Vts[0][0] : &Ks[0][0];
        const int row = qhalf * 32 + l32;
        #pragma unroll
        for (int c = 0; c < 4; c++) qf[c] = ldfr(Qsrc, row, c * 2 + hh);
    }
    __syncthreads();                    // all Q reads complete before K0/V0 DMA lands

    stage64(kptr, D_DIM, Ks[0],  wave, lane);
    stage64(vptr, S_LEN, Vts[0], wave, lane);

    f32x16 o0 = fzero16(), o1 = fzero16();   // O: col d = (dh*32)+l32, rows q per C layout
    float ls = 0.f;
    const int qg   = mytile * 64 + qhalf * 32 + l32;  // this lane's q row (global in head)
    const int kk4h = 4 * hh;

    for (int kt = 0; kt <= qb; kt++) {
        __syncthreads();                // K/V dbuf fence; drains prior DMA
        if (kt < qb) {
            stage64(kptr + (size_t)(kt + 1) * 64 * D_DIM, D_DIM, Ks[(kt + 1) & 1],  wave, lane);
            stage64(vptr + (kt + 1) * 64,                 S_LEN, Vts[(kt + 1) & 1], wave, lane);
        }
        if (kt > mytile) continue;      // inactive wave: staging + barrier only

        const u16* Kc = &Ks[kt & 1][0];
        const u16* Vc = &Vts[kt & 1][0];

        // ---- S^T = K Q^T (32x32x16): s0 = kk rows 0..31, s1 = 32..63 ----
        f32x16 s0 = fzero16(), s1 = fzero16();
        __builtin_amdgcn_s_setprio(1);
        #pragma unroll
        for (int c = 0; c < 4; c++) {
            bf16x8 ak0 = ldfr(Kc, l32,      c * 2 + hh);
            bf16x8 ak1 = ldfr(Kc, 32 + l32, c * 2 + hh);
            s0 = MFMA32(ak0, qf[c], s0);
            s1 = MFMA32(ak1, qf[c], s1);
        }
        __builtin_amdgcn_s_setprio(0);

        // ---- exp2 + causal mask; S C-layout: kk = (r&3)+8*(r>>2)+4*hh (+32 for s1) ----
        float pe0[16], pe1[16];
        if (kt == mytile) {
            #pragma unroll
            for (int r = 0; r < 16; r++) {
                const int kkg = kt * 64 + (r & 3) + 8 * (r >> 2) + kk4h;
                pe0[r] = (kkg      > qg) ? 0.f : fexp2(s0[r]);
                pe1[r] = (kkg + 32 > qg) ? 0.f : fexp2(s1[r]);
            }
        } else {
            #pragma unroll
            for (int r = 0; r < 16; r++) { pe0[r] = fexp2(s0[r]); pe1[r] = fexp2(s1[r]); }
        }
        #pragma unroll
        for (int r = 0; r < 16; r++) ls += pe0[r] + pe1[r];

        // ---- build PV A-fragments in-register (cvt_pk + permlane32_swap, T12) ----
        // Frag j consumes kk window [16j,16j+16); lane k-sub = hh*8. Reg pairing:
        // swap(cvtpk(r0,r1), cvtpk(r4,r5)) -> frag word0 & word2; same for r2..r7.
        bf16x8 pa[4];
#define BUILD_PA(PE, D0, D1)                                                      \
        {                                                                         \
            unsigned X0 = cvtpk(PE[0], PE[1]),   X1 = cvtpk(PE[2], PE[3]);        \
            unsigned Y0 = cvtpk(PE[4], PE[5]),   Y1 = cvtpk(PE[6], PE[7]);        \
            asm("v_permlane32_swap_b32 %0, %1" : "+v"(X0), "+v"(Y0));             \
            asm("v_permlane32_swap_b32 %0, %1" : "+v"(X1), "+v"(Y1));             \
            int4 f0; f0.x = (int)X0; f0.y = (int)X1; f0.z = (int)Y0; f0.w = (int)Y1; \
            D0 = *(bf16x8*)&f0;                                                   \
            unsigned Z0 = cvtpk(PE[8], PE[9]),   Z1 = cvtpk(PE[10], PE[11]);      \
            unsigned W0 = cvtpk(PE[12], PE[13]), W1 = cvtpk(PE[14], PE[15]);      \
            asm("v_permlane32_swap_b32 %0, %1" : "+v"(Z0), "+v"(W0));             \
            asm("v_permlane32_swap_b32 %0, %1" : "+v"(Z1), "+v"(W1));             \
            int4 f1; f1.x = (int)Z0; f1.y = (int)Z1; f1.z = (int)W0; f1.w = (int)W1; \
            D1 = *(bf16x8*)&f1;                                                   \
        }
        BUILD_PA(pe0, pa[0], pa[1]);
        BUILD_PA(pe1, pa[2], pa[3]);
#undef BUILD_PA

        // ---- PV (32x32x16): A = P[q][kk], B = V^T[d][kk] frags ----
        __builtin_amdgcn_s_setprio(1);
        #pragma unroll
        for (int j = 0; j < 4; j++) {
            bf16x8 bv0 = ldfr(Vc, l32,      j * 2 + hh);
            bf16x8 bv1 = ldfr(Vc, 32 + l32, j * 2 + hh);
            o0 = MFMA32(pa[j], bv0, o0);
            o1 = MFMA32(pa[j], bv1, o1);
        }
        __builtin_amdgcn_s_setprio(0);
    }

    // ---- epilogue: row sums -> Ls, normalize, store ----
    ls += __shfl_xor(ls, 32);           // full row sum for q col l32
    if (hh == 0) Ls[wave][l32] = ls;    // wave-private; within-wave lgkm ordering

    #pragma unroll
    for (int r = 0; r < 16; r++) {
        const int qlr = (r & 3) + 8 * (r >> 2) + kk4h;      // q local row 0..31
        const float li = frcp(Ls[wave][qlr]);
        const int qrow = mytile * 64 + qhalf * 32 + qlr;
        u16* dst = concat + ((size_t)(bb * S_LEN + qrow)) * E_DIM + hd * D_DIM;
        dst[l32]      = f2bf(o0[r] * li);
        dst[32 + l32] = f2bf(o1[r] * li);
    }
}

// ---------------- output projection: 64m x 128n tiles, 512 blocks (2/CU) (r7-frozen) ----------------
__global__ __launch_bounds__(256, 2) void out_proj(
    const u16* __restrict__ concat, const u16* __restrict__ wpt,
    const float* __restrict__ bp, float* __restrict__ out)
{
    const int bid = blockIdx.x;                        // 0..511
    const int mt  = (bid & 7) * 8 + ((bid >> 3) & 7);  // m-tile 0..63
    const int nt0 = bid >> 6;                          // n-tile 0..7
    const int m0 = mt * 64;
    const int n0 = nt0 * 128;

    __shared__ u16 As[2][64 * 64];
    __shared__ u16 Bs[2][128 * 64];

    const int tid  = threadIdx.x;
    const int wave = tid >> 6, lane = tid & 63, quad = lane >> 4, l16 = lane & 15;
    const int mh = wave >> 1, nh = wave & 1;

    f32x4 acc[4][2];
    #pragma unroll
    for (int j = 0; j < 4; j++)
        #pragma unroll
        for (int mi = 0; mi < 2; mi++) acc[j][mi] = fzero4();

    stage64(concat + (size_t)m0 * E_DIM, E_DIM, As[0], wave, lane);
    stage64(wpt + (size_t)n0 * E_DIM,        E_DIM, Bs[0],           wave, lane);
    stage64(wpt + (size_t)(n0 + 64) * E_DIM, E_DIM, Bs[0] + 64 * 64, wave, lane);

    for (int kt = 0; kt < 16; kt++) {
        __syncthreads();
        if (kt < 15) {
            const int k0 = (kt + 1) * 64;
            u16* an = As[(kt + 1) & 1];
            u16* bn = Bs[(kt + 1) & 1];
            stage64(concat + (size_t)m0 * E_DIM + k0, E_DIM, an, wave, lane);
            stage64(wpt + (size_t)n0 * E_DIM + k0,        E_DIM, bn,           wave, lane);
            stage64(wpt + (size_t)(n0 + 64) * E_DIM + k0, E_DIM, bn + 64 * 64, wave, lane);
        }
        const u16* Ac = As[kt & 1];
        const u16* Bc = Bs[kt & 1];

        #pragma unroll
        for (int kq = 0; kq < 2; kq++) {
            bf16x8 af[2];
            #pragma unroll
            for (int mi = 0; mi < 2; mi++)
                af[mi] = ldswz(Ac, mh * 32 + mi * 16 + l16, kq, quad);
            __builtin_amdgcn_s_setprio(1);
            #pragma unroll
            for (int j = 0; j < 4; j++) {
                bf16x8 bfv = ldswz(Bc, nh * 64 + j * 16 + l16, kq, quad);
                #pragma unroll
                for (int mi = 0; mi < 2; mi++)
                    acc[j][mi] = MFMA16(af[mi], bfv, acc[j][mi]);
            }
            __builtin_amdgcn_s_setprio(0);
        }
    }

    #pragma unroll
    for (int j = 0; j < 4; j++) {
        int n = n0 + nh * 64 + j * 16 + l16;
        float bia = bp[n];
        #pragma unroll
        for (int mi = 0; mi < 2; mi++) {
            #pragma unroll
            for (int r = 0; r < 4; r++) {
                int m = m0 + mh * 32 + mi * 16 + quad * 4 + r;
                out[(size_t)m * E_DIM + n] = fmaxf(acc[j][mi][r] + bia, 0.f);
            }
        }
    }
}

extern "C" void kernel_launch(void* const* d_in, const int* in_sizes, int n_in,
                              void* d_out, int out_size, void* d_ws, size_t ws_size,
                              hipStream_t stream)
{
    (void)in_sizes; (void)n_in; (void)out_size; (void)ws_size;
    const float* x  = (const float*)d_in[0];
    const float* Wq = (const float*)d_in[1];
    const float* Wk = (const float*)d_in[2];
    const float* Wv = (const float*)d_in[3];
    const float* bq = (const float*)d_in[4];
    const float* bk = (const float*)d_in[5];
    const float* bv = (const float*)d_in[6];
    const float* Wp = (const float*)d_in[7];
    const float* bp = (const float*)d_in[8];
    float* out = (float*)d_out;

    const size_t QKV_ELEMS = (size_t)2 * H_NUM * S_LEN * D_DIM;  // 4,194,304
    const size_t W_ELEMS   = (size_t)H_NUM * E_DIM * D_DIM;      // 1,048,576

    u16* q   = (u16*)d_ws;
    u16* k   = q   + QKV_ELEMS;
    u16* v   = k   + QKV_ELEMS;       // V^T [B,H,D,S], written directly by qkv_gemm
    u16* cc  = v   + QKV_ELEMS;
    u16* xb  = cc  + QKV_ELEMS;       // x bf16
    u16* wqt = xb  + QKV_ELEMS;       // [H][D][E] bf16  -- wqt||wkt||wvt = wcat [3072][1024]
    u16* wkt = wqt + W_ELEMS;
    u16* wvt = wkt + W_ELEMS;
    u16* wpt = wvt + W_ELEMS;         // [E][HD] bf16

    cvt_all<<<dim3(4096 + 768 + 256), 256, 0, stream>>>(
        x, xb, (int)QKV_ELEMS, Wq, Wk, Wv, wqt, wkt, wvt, Wp, wpt);

    qkv_gemm<<<dim3(32, 24), 128, 0, stream>>>(xb, wqt, bq, bk, bv, q, k, v);
    attn_fwd<<<dim3(512), 256, 0, stream>>>(q, k, v, cc);
    out_proj<<<dim3(512), 256, 0, stream>>>(cc, wpt, bp, out);
}

// Round 9
// 173.003 us; speedup vs baseline: 1.0318x; 1.0318x over previous
//
#include <hip/hip_runtime.h>

#define S_LEN 2048
#define E_DIM 1024
#define H_NUM 16
#define D_DIM 64

typedef unsigned short u16;
using bf16x8 = __attribute__((ext_vector_type(8))) short;   // 8 bf16 in 4 VGPRs
using f32x4  = __attribute__((ext_vector_type(4))) float;
using f32x16 = __attribute__((ext_vector_type(16))) float;

#define MFMA16(A, B, C) __builtin_amdgcn_mfma_f32_16x16x32_bf16(A, B, C, 0, 0, 0)
#define MFMA32(A, B, C) __builtin_amdgcn_mfma_f32_32x32x16_bf16(A, B, C, 0, 0, 0)
#define QSCALE 0.18033688011112042f   // (1/sqrt(D)) * log2(e), folded into Q so attn uses exp2

__device__ __forceinline__ u16 f2bf(float f) {
    unsigned u = __float_as_uint(f);
    u += 0x7fffu + ((u >> 16) & 1u);            // RNE
    return (u16)(u >> 16);
}
__device__ __forceinline__ f32x4 fzero4() { f32x4 z; z[0]=0.f; z[1]=0.f; z[2]=0.f; z[3]=0.f; return z; }
__device__ __forceinline__ f32x16 fzero16() {
    f32x16 z;
    #pragma unroll
    for (int i = 0; i < 16; i++) z[i] = 0.f;
    return z;
}

// packed f32x2 -> bf16x2 (RNE)
__device__ __forceinline__ unsigned cvtpk(float a, float b) {
    unsigned r;
    asm("v_cvt_pk_bf16_f32 %0, %1, %2" : "=v"(r) : "v"(a), "v"(b));
    return r;
}
__device__ __forceinline__ float fexp2(float x) {
#if __has_builtin(__builtin_amdgcn_exp2f)
    return __builtin_amdgcn_exp2f(x);
#else
    float r; asm("v_exp_f32 %0, %1" : "=v"(r) : "v"(x)); return r;
#endif
}
__device__ __forceinline__ float frcp(float x) {
#if __has_builtin(__builtin_amdgcn_rcpf)
    return __builtin_amdgcn_rcpf(x);
#else
    float r; asm("v_rcp_f32 %0, %1" : "=v"(r) : "v"(x)); return r;
#endif
}

// async global->LDS, 16B per lane; LDS dest = wave-uniform base + lane*16
__device__ __forceinline__ void gll16(const u16* g, u16* l) {
    __builtin_amdgcn_global_load_lds(
        (const __attribute__((address_space(1))) void*)g,
        (__attribute__((address_space(3))) void*)l, 16, 0, 0);
}

// ---- swizzled 64x64 u16 tile staging via global_load_lds (both-sides XOR swizzle) ----
// LDS row r at bytes r*128; physical 16B slot s holds logical slot s^(r&7).
__device__ __forceinline__ void stage64(const u16* __restrict__ g, int gstride,
                                        u16* l, int wave, int lane) {
    #pragma unroll
    for (int i = 0; i < 2; i++) {
        const int r  = wave * 16 + i * 8 + (lane >> 3);
        const int sl = (lane & 7) ^ (r & 7);
        gll16(g + (size_t)r * gstride + sl * 8, l + (wave * 16 + i * 8) * 64);
    }
}
// read one bf16x8 fragment = logical u16 cols [(hh*4+quad)*8 .. +7] of row rr
__device__ __forceinline__ bf16x8 ldswz(const u16* t, int rr, int hh, int quad) {
    const int sl = ((hh << 2) + quad) ^ (rr & 7);
    return *(const bf16x8*)(t + rr * 64 + sl * 8);
}
// generic fragment read: row rr (0..63), logical 16B slot sl (0..7)
__device__ __forceinline__ bf16x8 ldfr(const u16* t, int rr, int sl) {
    return *(const bf16x8*)(t + rr * 64 + ((sl ^ (rr & 7)) * 8));
}

// ---------------- fp32 [R,C] tile -> bf16 [C,R] transpose-convert helper ----------------
__device__ __forceinline__ void cvt_t_tile(const float* __restrict__ bin, u16* __restrict__ bout,
                                           int R, int C, int r0, int c0) {
    __shared__ float t[64][65];
    const int tid = threadIdx.x;
    const int lr = tid >> 2, lc = (tid & 3) * 16;

    const float* src = bin + (size_t)(r0 + lr) * C + c0 + lc;
    #pragma unroll
    for (int j = 0; j < 4; j++) {
        float4 f = *(const float4*)(src + j * 4);
        t[lr][lc + j * 4 + 0] = f.x; t[lr][lc + j * 4 + 1] = f.y;
        t[lr][lc + j * 4 + 2] = f.z; t[lr][lc + j * 4 + 3] = f.w;
    }
    __syncthreads();

    u16* dst = bout + (size_t)(c0 + lr) * R + r0 + lc;
    u16 vals[16];
    #pragma unroll
    for (int i = 0; i < 16; i++) vals[i] = f2bf(t[lc + i][lr]);
    uint4 pa, pb;
    pa.x = vals[0] | (vals[1] << 16);  pa.y = vals[2] | (vals[3] << 16);
    pa.z = vals[4] | (vals[5] << 16);  pa.w = vals[6] | (vals[7] << 16);
    pb.x = vals[8] | (vals[9] << 16);  pb.y = vals[10] | (vals[11] << 16);
    pb.z = vals[12] | (vals[13] << 16); pb.w = vals[14] | (vals[15] << 16);
    *(uint4*)dst = pa;
    *(uint4*)(dst + 8) = pb;
}

// ---------------- merged precompute: x->bf16 | Wq/Wk/Wv transpose | Wp transpose ----------------
__global__ __launch_bounds__(256) void cvt_all(
    const float* __restrict__ x, u16* __restrict__ xb, int n,
    const float* __restrict__ Wq, const float* __restrict__ Wk, const float* __restrict__ Wv,
    u16* __restrict__ wqt, u16* __restrict__ wkt, u16* __restrict__ wvt,
    const float* __restrict__ Wp, u16* __restrict__ wpt)
{
    const int bid = blockIdx.x;
    if (bid < 4096) {
        int i4 = (bid * 256 + threadIdx.x) * 4;
        if (i4 < n) {
            float4 f = *(const float4*)(x + i4);
            unsigned lo = (unsigned)f2bf(f.x) | ((unsigned)f2bf(f.y) << 16);
            unsigned hi = (unsigned)f2bf(f.z) | ((unsigned)f2bf(f.w) << 16);
            uint2 p; p.x = lo; p.y = hi;
            *(uint2*)(xb + i4) = p;
        }
    } else if (bid < 4096 + 768) {
        const int t  = bid - 4096;
        const int z  = t >> 4;           // 0..47
        const int ry = t & 15;           // 0..15
        const int which = z >> 4, bh = z & 15;
        const float* in = (which == 0) ? Wq : (which == 1) ? Wk : Wv;
        u16* outp = (which == 0) ? wqt : (which == 1) ? wkt : wvt;
        cvt_t_tile(in + (size_t)bh * E_DIM * D_DIM, outp + (size_t)bh * E_DIM * D_DIM,
                   E_DIM, D_DIM, ry * 64, 0);
    } else {
        const int t = bid - (4096 + 768); // 0..255
        cvt_t_tile(Wp, wpt, H_NUM * D_DIM, E_DIM, (t >> 4) * 64, (t & 15) * 64);
    }
}

// ---------------- QKV as one fused GEMM: M=4096, N=3072, K=1024 (r7-frozen) ----------------
__global__ __launch_bounds__(128, 2) void qkv_gemm(
    const u16* __restrict__ xb, const u16* __restrict__ wcat,
    const float* __restrict__ bq, const float* __restrict__ bk, const float* __restrict__ bv,
    u16* __restrict__ oq, u16* __restrict__ okk, u16* __restrict__ ov)
{
    const int m0 = blockIdx.x * 128;   // 0..31
    const int n0 = blockIdx.y * 128;   // 0..23

    __shared__ u16 As[2][64 * 64];     // 8 KB per buffer
    __shared__ u16 Bs[2][64 * 64];

    const int tid  = threadIdx.x;      // 0..127
    const int wave = tid >> 6, lane = tid & 63, quad = lane >> 4, l16 = lane & 15;

    f32x4 acc[8][4];                   // [j=n-frag 0..7][mi=m-frag 0..3]
    #pragma unroll
    for (int j = 0; j < 8; j++)
        #pragma unroll
        for (int mi = 0; mi < 4; mi++) acc[j][mi] = fzero4();

#define STAGE(K0, BUF)                                                               \
    _Pragma("unroll")                                                                \
    for (int i = 0; i < 2; i++) {                                                    \
        const int r  = wave * 32 + i * 8 + (lane >> 3);   /* LDS row 0..63 */        \
        const int s  = (lane & 7) ^ (r & 7);              /* logical slot  */        \
        const int mr = r + ((s >> 2) << 6);               /* m/n-row 0..127 */       \
        const int kc = (s & 3) * 8;                       /* k-col base     */       \
        gll16(xb   + (size_t)(m0 + mr) * E_DIM + (K0) + kc,                          \
              &As[BUF][(wave * 32 + i * 8) * 64]);                                   \
        gll16(wcat + (size_t)(n0 + mr) * E_DIM + (K0) + kc,                          \
              &Bs[BUF][(wave * 32 + i * 8) * 64]);                                   \
        const int r2  = wave * 32 + 16 + i * 8 + (lane >> 3);                        \
        const int s2  = (lane & 7) ^ (r2 & 7);                                       \
        const int mr2 = r2 + ((s2 >> 2) << 6);                                       \
        const int kc2 = (s2 & 3) * 8;                                                \
        gll16(xb   + (size_t)(m0 + mr2) * E_DIM + (K0) + kc2,                        \
              &As[BUF][(wave * 32 + 16 + i * 8) * 64]);                              \
        gll16(wcat + (size_t)(n0 + mr2) * E_DIM + (K0) + kc2,                        \
              &Bs[BUF][(wave * 32 + 16 + i * 8) * 64]);                              \
    }

    STAGE(0, 0);

    for (int kt = 0; kt < 32; kt++) {
        __syncthreads();
        if (kt < 31) {
            const int kn = (kt + 1) * 32;
            if ((kt & 1) == 0) { STAGE(kn, 1); } else { STAGE(kn, 0); }
        }
        const u16* Ac = As[kt & 1];
        const u16* Bc = Bs[kt & 1];

        bf16x8 af[4];
        #pragma unroll
        for (int mi = 0; mi < 4; mi++) {
            const int row = mi * 16 + l16;
            af[mi] = *(const bf16x8*)(&Ac[row * 64 + ((((wave << 2) + quad)) ^ (row & 7)) * 8]);
        }
        __builtin_amdgcn_s_setprio(1);
        #pragma unroll
        for (int j = 0; j < 8; j++) {
            const int row = (j & 3) * 16 + l16;
            bf16x8 bfv = *(const bf16x8*)(&Bc[row * 64 +
                              ((((j >> 2) << 2) + quad) ^ (row & 7)) * 8]);
            #pragma unroll
            for (int mi = 0; mi < 4; mi++)
                acc[j][mi] = MFMA16(af[mi], bfv, acc[j][mi]);
        }
        __builtin_amdgcn_s_setprio(0);
    }
#undef STAGE

    const int t = n0 >> 10;
    if (t < 2) {
        const float scl = (t == 0) ? QSCALE : 1.0f;
        const float* bias = (t == 0) ? bq : bk;
        u16* dst = (t == 0) ? oq : okk;
        #pragma unroll
        for (int j = 0; j < 8; j++) {
            const int n = n0 + j * 16 + l16;
            const int h = (n >> 6) & 15, d = n & 63;
            float bia = bias[h * D_DIM + d];
            #pragma unroll
            for (int mi = 0; mi < 4; mi++) {
                #pragma unroll
                for (int r = 0; r < 4; r++) {
                    int m = m0 + wave * 64 + mi * 16 + quad * 4 + r;
                    int b = m >> 11, s = m & 2047;
                    dst[((size_t)(b * H_NUM + h) * S_LEN + s) * D_DIM + d] =
                        f2bf((acc[j][mi][r] + bia) * scl);
                }
            }
        }
    } else {
        const int b  = m0 >> 11, s0 = m0 & 2047;
        const int h0 = (n0 >> 6) & 15;
        u16* Tb0 = &As[0][0];
        u16* Tb1 = &Bs[0][0];
        #pragma unroll
        for (int pass = 0; pass < 2; ++pass) {
            __syncthreads();
            if (wave == pass) {
                #pragma unroll
                for (int j = 0; j < 8; j++) {
                    const int n = n0 + j * 16 + l16;
                    const int d = n & 63, hh = (n >> 6) & 15;
                    const float bia = bv[hh * D_DIM + d];
                    u16* Tb = (j < 4) ? Tb0 : Tb1;
                    const int nl = (j & 3) * 16 + l16;
                    #pragma unroll
                    for (int mi = 0; mi < 4; mi++) {
                        uint2 pk;
                        pk.x = cvtpk(acc[j][mi][0] + bia, acc[j][mi][1] + bia);
                        pk.y = cvtpk(acc[j][mi][2] + bia, acc[j][mi][3] + bia);
                        *(uint2*)(&Tb[nl * 72 + mi * 16 + quad * 4]) = pk;
                    }
                }
            }
            __syncthreads();
            #pragma unroll
            for (int g = 0; g < 8; ++g) {
                const int rowi = g * 16 + (tid >> 3);
                const int ml = (tid & 7) * 8;
                const u16* srcp = (rowi < 64 ? Tb0 : Tb1) + (rowi & 63) * 72 + ml;
                const int hh = h0 + (rowi >> 6), d = rowi & 63;
                u16* dstp = ov + ((size_t)(b * H_NUM + hh) * D_DIM + d) * S_LEN
                               + s0 + pass * 64 + ml;
                *(uint4*)dstp = *(const uint4*)srcp;
            }
        }
    }
}

// ---------------- flash attention: 32x32 MFMA, in-register P, kk-SPLIT waves ----------------
// Round-9: wave w = (qhalf = w&1, kh = w>>1) owns the 32q x 32kk quadrant of BOTH
// tiles -> all 4 waves active every iteration (r8 dedicated waves to tiles: for
// kt > qa only 2/4 waves ran = 1 wave/SIMD, the r2 disease). This is r8's s0/s1
// halves reassigned to waves: K rows kh*32+l32, pe->pa windows j in {2kh, 2kh+1} —
// the verified BUILD_PA and layouts carry over unchanged. Partial-o along kk is
// summed once in the epilogue through the dead K/V LDS buffers (reused as f32).
__global__ __launch_bounds__(256, 2) void attn_fwd(
    const u16* __restrict__ q, const u16* __restrict__ k, const u16* __restrict__ vt,
    u16* __restrict__ concat)
{
    const int bid  = blockIdx.x;              // 0..511
    const int halfg = bid >> 8;               // 0 | 1
    const int pi   = (bid & 255) >> 5;        // 0..7
    const int p    = halfg ? (15 - pi) : pi;  // balanced: paired CUs sum to 49 iters
    const int g    = bid & 31;                // (b,h) group; XCD = g&7
    const int hd   = g & 15;
    const int bb   = g >> 4;
    const int qa = p, qb = 31 - p;

    const size_t headoff = (size_t)(bb * H_NUM + hd) * S_LEN * D_DIM;
    const u16* qptr = q  + headoff;
    const u16* kptr = k  + headoff;
    const u16* vptr = vt + headoff;     // [D][S]

    __shared__ u16 Ks[2][64 * 64];      // [kk][d], swizzled, dbuf; f32 o-reduce tile b in epilogue
    __shared__ u16 Vts[2][64 * 64];     // [d][sk], swizzled, dbuf; f32 o-reduce tile a in epilogue
    __shared__ float Lsb[2][2][32];     // [kh][qhalf][q] partial row sums, tile b
    __shared__ float Lsa[2][2][32];     // tile a

    const int tid  = threadIdx.x;
    const int wave = tid >> 6, lane = tid & 63;
    const int l32 = lane & 31, hh = lane >> 5;
    const int qhalf = wave & 1, kh = wave >> 1;

    // ---- prologue: stage Q tiles through the K/V buffers, hoist to registers ----
    stage64(qptr + (size_t)qb * 64 * D_DIM, D_DIM, Ks[0],  wave, lane);
    stage64(qptr + (size_t)qa * 64 * D_DIM, D_DIM, Vts[0], wave, lane);
    __syncthreads();                    // drains DMA

    bf16x8 qfb[4], qfa[4];              // B-operand: col q = l32 (own qhalf), k(d) = c*16 + hh*8
    {
        const int row = qhalf * 32 + l32;
        #pragma unroll
        for (int c = 0; c < 4; c++) {
            qfb[c] = ldfr(&Ks[0][0],  row, c * 2 + hh);
            qfa[c] = ldfr(&Vts[0][0], row, c * 2 + hh);
        }
    }
    __syncthreads();                    // all Q reads complete before K0/V0 DMA lands

    stage64(kptr, D_DIM, Ks[0],  wave, lane);
    stage64(vptr, S_LEN, Vts[0], wave, lane);

    f32x16 ob0 = fzero16(), ob1 = fzero16();   // tile b partial O (kk-half kh): d = l32 / 32+l32
    f32x16 oa0 = fzero16(), oa1 = fzero16();   // tile a
    float lsb = 0.f, lsa = 0.f;
    const int qgb = qb * 64 + qhalf * 32 + l32;
    const int qga = qa * 64 + qhalf * 32 + l32;
    const int kkbase = kh * 32 + 4 * hh;        // + (r&3) + 8*(r>>2)

#define BUILD_PA(PE, D0, D1)                                                      \
        {                                                                         \
            unsigned X0 = cvtpk(PE[0], PE[1]),   X1 = cvtpk(PE[2], PE[3]);        \
            unsigned Y0 = cvtpk(PE[4], PE[5]),   Y1 = cvtpk(PE[6], PE[7]);        \
            asm("v_permlane32_swap_b32 %0, %1" : "+v"(X0), "+v"(Y0));             \
            asm("v_permlane32_swap_b32 %0, %1" : "+v"(X1), "+v"(Y1));             \
            int4 f0; f0.x = (int)X0; f0.y = (int)X1; f0.z = (int)Y0; f0.w = (int)Y1; \
            D0 = *(bf16x8*)&f0;                                                   \
            unsigned Z0 = cvtpk(PE[8], PE[9]),   Z1 = cvtpk(PE[10], PE[11]);      \
            unsigned W0 = cvtpk(PE[12], PE[13]), W1 = cvtpk(PE[14], PE[15]);      \
            asm("v_permlane32_swap_b32 %0, %1" : "+v"(Z0), "+v"(W0));             \
            asm("v_permlane32_swap_b32 %0, %1" : "+v"(Z1), "+v"(W1));             \
            int4 f1; f1.x = (int)Z0; f1.y = (int)Z1; f1.z = (int)W0; f1.w = (int)W1; \
            D1 = *(bf16x8*)&f1;                                                   \
        }

    for (int kt = 0; kt <= qb; kt++) {
        __syncthreads();                // K/V dbuf fence; drains prior DMA
        if (kt < qb) {
            stage64(kptr + (size_t)(kt + 1) * 64 * D_DIM, D_DIM, Ks[(kt + 1) & 1],  wave, lane);
            stage64(vptr + (kt + 1) * 64,                 S_LEN, Vts[(kt + 1) & 1], wave, lane);
        }
        const u16* Kc = &Ks[kt & 1][0];
        const u16* Vc = &Vts[kt & 1][0];

        // ================= tile b (all waves, every iteration) =================
        {
            f32x16 s = fzero16();
            __builtin_amdgcn_s_setprio(1);
            #pragma unroll
            for (int c = 0; c < 4; c++) {
                bf16x8 ak = ldfr(Kc, kh * 32 + l32, c * 2 + hh);
                s = MFMA32(ak, qfb[c], s);
            }
            __builtin_amdgcn_s_setprio(0);

            float pe[16];
            if (kt == qb) {
                #pragma unroll
                for (int r = 0; r < 16; r++) {
                    const int kkg = kt * 64 + kkbase + (r & 3) + 8 * (r >> 2);
                    pe[r] = (kkg > qgb) ? 0.f : fexp2(s[r]);
                }
            } else {
                #pragma unroll
                for (int r = 0; r < 16; r++) pe[r] = fexp2(s[r]);
            }
            #pragma unroll
            for (int r = 0; r < 16; r++) lsb += pe[r];

            bf16x8 pa0, pa1;
            BUILD_PA(pe, pa0, pa1);

            __builtin_amdgcn_s_setprio(1);
            {
                bf16x8 v00 = ldfr(Vc, l32,      (2 * kh    ) * 2 + hh);
                bf16x8 v10 = ldfr(Vc, 32 + l32, (2 * kh    ) * 2 + hh);
                bf16x8 v01 = ldfr(Vc, l32,      (2 * kh + 1) * 2 + hh);
                bf16x8 v11 = ldfr(Vc, 32 + l32, (2 * kh + 1) * 2 + hh);
                ob0 = MFMA32(pa0, v00, ob0);
                ob1 = MFMA32(pa0, v10, ob1);
                ob0 = MFMA32(pa1, v01, ob0);
                ob1 = MFMA32(pa1, v11, ob1);
            }
            __builtin_amdgcn_s_setprio(0);
        }

        // ================= tile a (all waves, while kt <= qa) =================
        if (kt <= qa) {
            f32x16 s = fzero16();
            __builtin_amdgcn_s_setprio(1);
            #pragma unroll
            for (int c = 0; c < 4; c++) {
                bf16x8 ak = ldfr(Kc, kh * 32 + l32, c * 2 + hh);
                s = MFMA32(ak, qfa[c], s);
            }
            __builtin_amdgcn_s_setprio(0);

            float pe[16];
            if (kt == qa) {
                #pragma unroll
                for (int r = 0; r < 16; r++) {
                    const int kkg = kt * 64 + kkbase + (r & 3) + 8 * (r >> 2);
                    pe[r] = (kkg > qga) ? 0.f : fexp2(s[r]);
                }
            } else {
                #pragma unroll
                for (int r = 0; r < 16; r++) pe[r] = fexp2(s[r]);
            }
            #pragma unroll
            for (int r = 0; r < 16; r++) lsa += pe[r];

            bf16x8 pa0, pa1;
            BUILD_PA(pe, pa0, pa1);

            __builtin_amdgcn_s_setprio(1);
            {
                bf16x8 v00 = ldfr(Vc, l32,      (2 * kh    ) * 2 + hh);
                bf16x8 v10 = ldfr(Vc, 32 + l32, (2 * kh    ) * 2 + hh);
                bf16x8 v01 = ldfr(Vc, l32,      (2 * kh + 1) * 2 + hh);
                bf16x8 v11 = ldfr(Vc, 32 + l32, (2 * kh + 1) * 2 + hh);
                oa0 = MFMA32(pa0, v00, oa0);
                oa1 = MFMA32(pa0, v10, oa1);
                oa0 = MFMA32(pa1, v01, oa0);
                oa1 = MFMA32(pa1, v11, oa1);
            }
            __builtin_amdgcn_s_setprio(0);
        }
    }
#undef BUILD_PA

    // ---- epilogue: cross-wave (kh) reduction through dead K/V LDS, normalize, store ----
    __syncthreads();                    // all K/V reads done; buffers reusable as f32

    lsb += __shfl_xor(lsb, 32);         // sum over this wave's 32 kk rows, q = qhalf*32+l32
    lsa += __shfl_xor(lsa, 32);
    if (hh == 0) {
        Lsb[kh][qhalf][l32] = lsb;
        Lsa[kh][qhalf][l32] = lsa;
    }

    float* Rb = (float*)(&Ks[0][0])  + qhalf * 2048;    // [32 q][64 d] f32 per qhalf
    float* Ra = (float*)(&Vts[0][0]) + qhalf * 2048;

    if (kh == 1) {
        #pragma unroll
        for (int r = 0; r < 16; r++) {
            const int qlr = (r & 3) + 8 * (r >> 2) + 4 * hh;
            Rb[qlr * 64 + l32]      = ob0[r];
            Rb[qlr * 64 + 32 + l32] = ob1[r];
            Ra[qlr * 64 + l32]      = oa0[r];
            Ra[qlr * 64 + 32 + l32] = oa1[r];
        }
    }
    __syncthreads();

    if (kh == 0) {
        #pragma unroll
        for (int r = 0; r < 16; r++) {
            const int qlr = (r & 3) + 8 * (r >> 2) + 4 * hh;
            const float lib = frcp(Lsb[0][qhalf][qlr] + Lsb[1][qhalf][qlr]);
            const float lia = frcp(Lsa[0][qhalf][qlr] + Lsa[1][qhalf][qlr]);
            const float vb0 = ob0[r] + Rb[qlr * 64 + l32];
            const float vb1 = ob1[r] + Rb[qlr * 64 + 32 + l32];
            const float va0 = oa0[r] + Ra[qlr * 64 + l32];
            const float va1 = oa1[r] + Ra[qlr * 64 + 32 + l32];
            const int qrb = qb * 64 + qhalf * 32 + qlr;
            const int qra = qa * 64 + qhalf * 32 + qlr;
            u16* db = concat + ((size_t)(bb * S_LEN + qrb)) * E_DIM + hd * D_DIM;
            u16* da = concat + ((size_t)(bb * S_LEN + qra)) * E_DIM + hd * D_DIM;
            db[l32]      = f2bf(vb0 * lib);
            db[32 + l32] = f2bf(vb1 * lib);
            da[l32]      = f2bf(va0 * lia);
            da[32 + l32] = f2bf(va1 * lia);
        }
    }
}

// ---------------- output projection: 64m x 128n tiles, 512 blocks (2/CU) (r7-frozen) ----------------
__global__ __launch_bounds__(256, 2) void out_proj(
    const u16* __restrict__ concat, const u16* __restrict__ wpt,
    const float* __restrict__ bp, float* __restrict__ out)
{
    const int bid = blockIdx.x;                        // 0..511
    const int mt  = (bid & 7) * 8 + ((bid >> 3) & 7);  // m-tile 0..63
    const int nt0 = bid >> 6;                          // n-tile 0..7
    const int m0 = mt * 64;
    const int n0 = nt0 * 128;

    __shared__ u16 As[2][64 * 64];
    __shared__ u16 Bs[2][128 * 64];

    const int tid  = threadIdx.x;
    const int wave = tid >> 6, lane = tid & 63, quad = lane >> 4, l16 = lane & 15;
    const int mh = wave >> 1, nh = wave & 1;

    f32x4 acc[4][2];
    #pragma unroll
    for (int j = 0; j < 4; j++)
        #pragma unroll
        for (int mi = 0; mi < 2; mi++) acc[j][mi] = fzero4();

    stage64(concat + (size_t)m0 * E_DIM, E_DIM, As[0], wave, lane);
    stage64(wpt + (size_t)n0 * E_DIM,        E_DIM, Bs[0],           wave, lane);
    stage64(wpt + (size_t)(n0 + 64) * E_DIM, E_DIM, Bs[0] + 64 * 64, wave, lane);

    for (int kt = 0; kt < 16; kt++) {
        __syncthreads();
        if (kt < 15) {
            const int k0 = (kt + 1) * 64;
            u16* an = As[(kt + 1) & 1];
            u16* bn = Bs[(kt + 1) & 1];
            stage64(concat + (size_t)m0 * E_DIM + k0, E_DIM, an, wave, lane);
            stage64(wpt + (size_t)n0 * E_DIM + k0,        E_DIM, bn,           wave, lane);
            stage64(wpt + (size_t)(n0 + 64) * E_DIM + k0, E_DIM, bn + 64 * 64, wave, lane);
        }
        const u16* Ac = As[kt & 1];
        const u16* Bc = Bs[kt & 1];

        #pragma unroll
        for (int kq = 0; kq < 2; kq++) {
            bf16x8 af[2];
            #pragma unroll
            for (int mi = 0; mi < 2; mi++)
                af[mi] = ldswz(Ac, mh * 32 + mi * 16 + l16, kq, quad);
            __builtin_amdgcn_s_setprio(1);
            #pragma unroll
            for (int j = 0; j < 4; j++) {
                bf16x8 bfv = ldswz(Bc, nh * 64 + j * 16 + l16, kq, quad);
                #pragma unroll
                for (int mi = 0; mi < 2; mi++)
                    acc[j][mi] = MFMA16(af[mi], bfv, acc[j][mi]);
            }
            __builtin_amdgcn_s_setprio(0);
        }
    }

    #pragma unroll
    for (int j = 0; j < 4; j++) {
        int n = n0 + nh * 64 + j * 16 + l16;
        float bia = bp[n];
        #pragma unroll
        for (int mi = 0; mi < 2; mi++) {
            #pragma unroll
            for (int r = 0; r < 4; r++) {
                int m = m0 + mh * 32 + mi * 16 + quad * 4 + r;
                out[(size_t)m * E_DIM + n] = fmaxf(acc[j][mi][r] + bia, 0.f);
            }
        }
    }
}

extern "C" void kernel_launch(void* const* d_in, const int* in_sizes, int n_in,
                              void* d_out, int out_size, void* d_ws, size_t ws_size,
                              hipStream_t stream)
{
    (void)in_sizes; (void)n_in; (void)out_size; (void)ws_size;
    const float* x  = (const float*)d_in[0];
    const float* Wq = (const float*)d_in[1];
    const float* Wk = (const float*)d_in[2];
    const float* Wv = (const float*)d_in[3];
    const float* bq = (const float*)d_in[4];
    const float* bk = (const float*)d_in[5];
    const float* bv = (const float*)d_in[6];
    const float* Wp = (const float*)d_in[7];
    const float* bp = (const float*)d_in[8];
    float* out = (float*)d_out;

    const size_t QKV_ELEMS = (size_t)2 * H_NUM * S_LEN * D_DIM;  // 4,194,304
    const size_t W_ELEMS   = (size_t)H_NUM * E_DIM * D_DIM;      // 1,048,576

    u16* q   = (u16*)d_ws;
    u16* k   = q   + QKV_ELEMS;
    u16* v   = k   + QKV_ELEMS;       // V^T [B,H,D,S], written directly by qkv_gemm
    u16* cc  = v   + QKV_ELEMS;
    u16* xb  = cc  + QKV_ELEMS;       // x bf16
    u16* wqt = xb  + QKV_ELEMS;       // [H][D][E] bf16  -- wqt||wkt||wvt = wcat [3072][1024]
    u16* wkt = wqt + W_ELEMS;
    u16* wvt = wkt + W_ELEMS;
    u16* wpt = wvt + W_ELEMS;         // [E][HD] bf16

    cvt_all<<<dim3(4096 + 768 + 256), 256, 0, stream>>>(
        x, xb, (int)QKV_ELEMS, Wq, Wk, Wv, wqt, wkt, wvt, Wp, wpt);

    qkv_gemm<<<dim3(32, 24), 128, 0, stream>>>(xb, wqt, bq, bk, bv, q, k, v);
    attn_fwd<<<dim3(512), 256, 0, stream>>>(q, k, v, cc);
    out_proj<<<dim3(512), 256, 0, stream>>>(cc, wpt, bp, out);
}